// Round 1
// baseline (657.410 us; speedup 1.0000x reference)
//
#include <hip/hip_runtime.h>
#include <math.h>

#define BB 4
#define TT 4096
#define DD 4096
#define NE 64
#define NTOK (BB * TT)        // 16384
#define TOPK 2
#define TW 8                  // tokens per wave
#define KC 64                 // K chunk staged in LDS
#define NWAVES 4
#define BLOCK (NWAVES * 64)   // 256
#define TOKPB (NWAVES * TW)   // 32 tokens per block
#define LDSTR 65              // +1 pad: (lane + j) % 32 -> 2-way (free)

__global__ __launch_bounds__(BLOCK) void router_kernel(
    const float* __restrict__ x, const float* __restrict__ gw,
    float* __restrict__ out, float* __restrict__ ws) {
  __shared__ float wt[NE * LDSTR];

  const int tid = threadIdx.x;
  const int lane = tid & 63;                  // lane == expert index
  int tok0 = blockIdx.x * TOKPB + (tid >> 6) * TW;
  tok0 = __builtin_amdgcn_readfirstlane(tok0);  // force wave-uniform -> s_load for x

  float acc[TW];
#pragma unroll
  for (int t = 0; t < TW; ++t) acc[t] = 0.f;

  for (int k0 = 0; k0 < DD; k0 += KC) {
    __syncthreads();
    // stage gate_w[e][k0..k0+KC) -> wt[e*65 + j]; 4096 floats, 16 per thread
#pragma unroll
    for (int r = 0; r < (NE * KC) / (BLOCK * 4); ++r) {  // 4
      int idx = r * BLOCK + tid;
      int e = idx >> 4;
      int j4 = idx & 15;
      const float4 v =
          *reinterpret_cast<const float4*>(gw + (size_t)e * DD + k0 + j4 * 4);
      float* dst = &wt[e * LDSTR + j4 * 4];
      dst[0] = v.x; dst[1] = v.y; dst[2] = v.z; dst[3] = v.w;
    }
    __syncthreads();
    // compute: register-cache 16 weights, sweep 8 tokens (x via scalar loads)
#pragma unroll
    for (int jb = 0; jb < KC; jb += 16) {
      float wr[16];
#pragma unroll
      for (int j = 0; j < 16; ++j) wr[j] = wt[lane * LDSTR + jb + j];
#pragma unroll
      for (int t = 0; t < TW; ++t) {
        const float* xr = x + (size_t)(tok0 + t) * DD + k0 + jb;
#pragma unroll
        for (int j = 0; j < 16; ++j) acc[t] = fmaf(xr[j], wr[j], acc[t]);
      }
    }
  }

  // per-token softmax + top-2 across the 64 lanes (= 64 experts)
  float psum_local = 0.f;
  float cnt_local = 0.f;
  float* out_v = out;                 // (NTOK, 2) top-k vals
  float* out_i = out + NTOK * TOPK;   // (NTOK, 2) top-k idx as float
#pragma unroll 1
  for (int t = 0; t < TW; ++t) {
    float v = acc[t];
    float m = v;
#pragma unroll
    for (int s = 32; s > 0; s >>= 1) m = fmaxf(m, __shfl_xor(m, s, 64));
    float ex = expf(v - m);
    float ssum = ex;
#pragma unroll
    for (int s = 32; s > 0; s >>= 1) ssum += __shfl_xor(ssum, s, 64);
    float p = ex / ssum;
    psum_local += p;

    // top-1 (ties -> lowest index, matching jax.lax.top_k)
    float v1 = p; int i1 = lane;
#pragma unroll
    for (int s = 32; s > 0; s >>= 1) {
      float ov = __shfl_xor(v1, s, 64);
      int   oi = __shfl_xor(i1, s, 64);
      if (ov > v1 || (ov == v1 && oi < i1)) { v1 = ov; i1 = oi; }
    }
    // top-2: mask out i1, reduce again
    float v2 = (lane == i1) ? -INFINITY : p; int i2 = lane;
#pragma unroll
    for (int s = 32; s > 0; s >>= 1) {
      float ov = __shfl_xor(v2, s, 64);
      int   oi = __shfl_xor(i2, s, 64);
      if (ov > v2 || (ov == v2 && oi < i2)) { v2 = ov; i2 = oi; }
    }

    cnt_local += (lane == i1 ? 1.f : 0.f) + (lane == i2 ? 1.f : 0.f);
    if (lane == 0) {
      int tg = tok0 + t;
      out_v[tg * 2 + 0] = v1;
      out_v[tg * 2 + 1] = v2;
      out_i[tg * 2 + 0] = (float)i1;
      out_i[tg * 2 + 1] = (float)i2;
    }
  }
  // loss partials: ws[0:64] = counts, ws[64:128] = prob sums
  atomicAdd(ws + lane, cnt_local);
  atomicAdd(ws + NE + lane, psum_local);
}

__global__ void loss_kernel(const float* __restrict__ ws,
                            float* __restrict__ out) {
  int lane = threadIdx.x & 63;
  float f = ws[lane] * (1.f / (float)(NTOK * TOPK));
  float p = ws[NE + lane] * (1.f / (float)NTOK);
  float v = f * p;  // loss = E * mean_i(f_i p_i) = sum_i f_i p_i
#pragma unroll
  for (int s = 32; s > 0; s >>= 1) v += __shfl_xor(v, s, 64);
  if (lane == 0) out[NTOK * TOPK * 2] = v;
}

extern "C" void kernel_launch(void* const* d_in, const int* in_sizes, int n_in,
                              void* d_out, int out_size, void* d_ws,
                              size_t ws_size, hipStream_t stream) {
  const float* x  = (const float*)d_in[0];
  const float* gw = (const float*)d_in[1];
  float* out = (float*)d_out;
  float* ws  = (float*)d_ws;

  hipMemsetAsync(d_ws, 0, 2 * NE * sizeof(float), stream);
  router_kernel<<<NTOK / TOKPB, BLOCK, 0, stream>>>(x, gw, out, ws);
  loss_kernel<<<1, 64, 0, stream>>>(ws, out);
}

// Round 2
// 415.404 us; speedup vs baseline: 1.5826x; 1.5826x over previous
//
#include <hip/hip_runtime.h>
#include <math.h>

#define NE 64
#define NTOK 16384
#define DD 4096
#define TOPK 2
#define NW 8                  // waves per block (K-split factor)
#define BLOCK (NW * 64)       // 512
#define TOKPB 64              // tokens per block (= lanes)
#define KRANGE (DD / NW)      // 512 k per wave
#define KC 16                 // k chunk held in registers
#define NCH (KRANGE / KC)     // 32 chunks
#define LDSTR 65              // logit tile stride (+1 pad -> conflict-free)

__global__ __launch_bounds__(BLOCK) void router_kernel(
    const float* __restrict__ x, const float* __restrict__ gw,
    float* __restrict__ out, float* __restrict__ ws) {
  __shared__ float lg[TOKPB * LDSTR];

  const int tid = threadIdx.x;
  const int lane = tid & 63;  // lane == token within block
  const int wid = __builtin_amdgcn_readfirstlane(tid >> 6);
  const int tok0 = blockIdx.x * TOKPB;

  // per-lane x row slice (VGPR addressing, one 64B line per chunk)
  const float* xrow = x + (size_t)(tok0 + lane) * DD + wid * KRANGE;
  // wave-uniform weight base (SGPR addressing -> s_load)
  const float* wbase = gw + wid * KRANGE;

  float acc[NE];
#pragma unroll
  for (int e = 0; e < NE; ++e) acc[e] = 0.f;

  // prefetch first x chunk
  float4 xb0 = *(const float4*)(xrow + 0);
  float4 xb1 = *(const float4*)(xrow + 4);
  float4 xb2 = *(const float4*)(xrow + 8);
  float4 xb3 = *(const float4*)(xrow + 12);

#pragma unroll 1
  for (int c = 0; c < NCH; ++c) {
    float xr[KC];
    xr[0] = xb0.x; xr[1] = xb0.y; xr[2] = xb0.z; xr[3] = xb0.w;
    xr[4] = xb1.x; xr[5] = xb1.y; xr[6] = xb1.z; xr[7] = xb1.w;
    xr[8] = xb2.x; xr[9] = xb2.y; xr[10] = xb2.z; xr[11] = xb2.w;
    xr[12] = xb3.x; xr[13] = xb3.y; xr[14] = xb3.z; xr[15] = xb3.w;
    if (c + 1 < NCH) {  // prefetch next chunk during FMAs
      const float* nx = xrow + (c + 1) * KC;
      xb0 = *(const float4*)(nx + 0);
      xb1 = *(const float4*)(nx + 4);
      xb2 = *(const float4*)(nx + 8);
      xb3 = *(const float4*)(nx + 12);
    }
    const float* wc = wbase + c * KC;
#pragma unroll
    for (int e = 0; e < NE; ++e) {
      const float* wr = wc + (size_t)e * DD;  // uniform -> s_load_dwordx16
      float a = acc[e];
#pragma unroll
      for (int j = 0; j < KC; ++j) a = fmaf(xr[j], wr[j], a);
      acc[e] = a;
    }
  }

  // cross-wave reduction of partial logits into lg[tok][e]
#pragma unroll 1
  for (int w = 0; w < NW; ++w) {
    __syncthreads();
    if (wid == w) {
      if (w == 0) {
#pragma unroll
        for (int e = 0; e < NE; ++e) lg[lane * LDSTR + e] = acc[e];
      } else {
#pragma unroll
        for (int e = 0; e < NE; ++e) lg[lane * LDSTR + e] += acc[e];
      }
    }
  }
  __syncthreads();

  // epilogue: wave wid handles tokens wid*8 .. wid*8+7; lane == expert
  float psum_local = 0.f;
  float cnt_local = 0.f;
  float* out_v = out;                // (NTOK, 2) top-k vals
  float* out_i = out + NTOK * TOPK;  // (NTOK, 2) top-k idx as float
#pragma unroll 1
  for (int i = 0; i < TOKPB / NW; ++i) {
    const int t = wid * (TOKPB / NW) + i;
    float v = lg[t * LDSTR + lane];
    float m = v;
#pragma unroll
    for (int s = 32; s > 0; s >>= 1) m = fmaxf(m, __shfl_xor(m, s, 64));
    float ex = expf(v - m);
    float ssum = ex;
#pragma unroll
    for (int s = 32; s > 0; s >>= 1) ssum += __shfl_xor(ssum, s, 64);
    float p = ex / ssum;
    psum_local += p;

    // top-1 (ties -> lowest index, matching jax.lax.top_k)
    float v1 = p; int i1 = lane;
#pragma unroll
    for (int s = 32; s > 0; s >>= 1) {
      float ov = __shfl_xor(v1, s, 64);
      int oi = __shfl_xor(i1, s, 64);
      if (ov > v1 || (ov == v1 && oi < i1)) { v1 = ov; i1 = oi; }
    }
    // top-2: mask out i1, reduce again
    float v2 = (lane == i1) ? -INFINITY : p; int i2 = lane;
#pragma unroll
    for (int s = 32; s > 0; s >>= 1) {
      float ov = __shfl_xor(v2, s, 64);
      int oi = __shfl_xor(i2, s, 64);
      if (ov > v2 || (ov == v2 && oi < i2)) { v2 = ov; i2 = oi; }
    }

    cnt_local += (lane == i1 ? 1.f : 0.f) + (lane == i2 ? 1.f : 0.f);
    if (lane == 0) {
      const int tg = tok0 + t;
      out_v[tg * 2 + 0] = v1;
      out_v[tg * 2 + 1] = v2;
      out_i[tg * 2 + 0] = (float)i1;
      out_i[tg * 2 + 1] = (float)i2;
    }
  }
  // loss partials: ws[0:64] = pick counts, ws[64:128] = prob sums
  atomicAdd(ws + lane, cnt_local);
  atomicAdd(ws + NE + lane, psum_local);
}

__global__ void loss_kernel(const float* __restrict__ ws,
                            float* __restrict__ out) {
  const int lane = threadIdx.x & 63;
  float f = ws[lane] * (1.f / (float)(NTOK * TOPK));
  float p = ws[NE + lane] * (1.f / (float)NTOK);
  float v = f * p;  // loss = E * mean_i(f_i p_i) = sum_i f_i p_i
#pragma unroll
  for (int s = 32; s > 0; s >>= 1) v += __shfl_xor(v, s, 64);
  if (lane == 0) out[NTOK * TOPK * 2] = v;
}

extern "C" void kernel_launch(void* const* d_in, const int* in_sizes, int n_in,
                              void* d_out, int out_size, void* d_ws,
                              size_t ws_size, hipStream_t stream) {
  const float* x = (const float*)d_in[0];
  const float* gw = (const float*)d_in[1];
  float* out = (float*)d_out;
  float* ws = (float*)d_ws;

  hipMemsetAsync(d_ws, 0, 2 * NE * sizeof(float), stream);
  router_kernel<<<NTOK / TOKPB, BLOCK, 0, stream>>>(x, gw, out, ws);
  loss_kernel<<<1, 64, 0, stream>>>(ws, out);
}